// Round 1
// baseline (284.933 us; speedup 1.0000x reference)
//
#include <hip/hip_runtime.h>

#define LEAK 0.2f

typedef float f32x4 __attribute__((ext_vector_type(4)));
typedef short s16x8 __attribute__((ext_vector_type(8)));

__device__ __forceinline__ float leaky(float x){ return fmaxf(x, 0.f) + LEAK * fminf(x, 0.f); }

__device__ __forceinline__ short f2bf(float f){
    unsigned u = __builtin_bit_cast(unsigned, f);
    u = (u + 0x7FFFu + ((u >> 16) & 1u)) >> 16;   // RNE
    return (short)u;
}

// ---------------------------------------------------------------------------
// K1: A matrix, sparsity loss, DAG loss (one block, 1024 threads)
// ---------------------------------------------------------------------------
__global__ void k_setup(const float* __restrict__ lw, float* __restrict__ A,
                        float* __restrict__ acc)
{
    __shared__ float A2s[1024], mp[1024], red[1024];
    const int t = threadIdx.x;
    const int r = t >> 5, c = t & 31;
    float v = lw[t];
    float sig = 1.f / (1.f + expf(-v));
    // lw*upper - 10*eye, then /TEMP(=0.1)
    float l2 = (r < c) ? v * 10.f : ((r == c) ? -100.f : 0.f);
    A[t] = 1.f / (1.f + expf(-l2));
    red[t] = sig;                 // sparsity: sum |sigmoid| = sum sigmoid
    float a2 = sig * sig;
    A2s[t] = a2; mp[t] = a2;
    __syncthreads();
    for (int s = 512; s > 0; s >>= 1){ if (t < s) red[t] += red[t + s]; __syncthreads(); }
    if (t == 0) acc[2] = red[0];

    const float invf[10] = {0.f, 1.f, 0.5f, 1.6666667e-1f, 4.1666667e-2f,
                            8.3333333e-3f, 1.3888889e-3f, 1.9841270e-4f,
                            2.4801587e-5f, 2.7557319e-6f};
    float tr = 0.f;
    for (int n = 1; n <= 9; ++n){
        __syncthreads();
        if (t == 0){
            float s = 0.f;
            for (int k2 = 0; k2 < 32; ++k2) s += mp[k2 * 33];
            tr += s * invf[n];
        }
        if (n == 9) break;
        float a = 0.f;
        for (int k2 = 0; k2 < 32; ++k2) a += mp[r * 32 + k2] * A2s[k2 * 32 + c];
        __syncthreads();
        mp[t] = a;
    }
    if (t == 0) acc[3] = tr * tr;   // dag = (trace(expm) - S)^2
}

// ---------------------------------------------------------------------------
// K2/K6: fp32 tiled GEMM, M=4096 K=512 N=512, 64x64 tile, BK=16, 4x4 microtile
// ---------------------------------------------------------------------------
template<bool DOLEAKY, bool DOLOSS>
__global__ __launch_bounds__(256) void k_gemm512(
    const float* __restrict__ Am, const float* __restrict__ Bm,
    const float* __restrict__ bias, float* __restrict__ Cm,
    const float* __restrict__ feat, float* __restrict__ acc)
{
    __shared__ float As[16][65];
    __shared__ float Bs[16][64];
    __shared__ float red[256];
    const int t = threadIdx.x;
    const int bm0 = blockIdx.x * 64, bn0 = blockIdx.y * 64;
    const int tm = t >> 4, tn = t & 15;
    const int lm = t >> 2, lkq = t & 3;
    const int lk = t >> 4, lnq = t & 15;
    float accr[4][4] = {};
    for (int k0 = 0; k0 < 512; k0 += 16){
        __syncthreads();
        f32x4 av = *(const f32x4*)&Am[(size_t)(bm0 + lm) * 512 + k0 + lkq * 4];
        As[lkq * 4 + 0][lm] = av[0]; As[lkq * 4 + 1][lm] = av[1];
        As[lkq * 4 + 2][lm] = av[2]; As[lkq * 4 + 3][lm] = av[3];
        f32x4 bv = *(const f32x4*)&Bm[(size_t)(k0 + lk) * 512 + bn0 + lnq * 4];
        *(f32x4*)&Bs[lk][lnq * 4] = bv;
        __syncthreads();
        #pragma unroll
        for (int kk = 0; kk < 16; ++kk){
            f32x4 b4 = *(const f32x4*)&Bs[kk][tn * 4];
            float a0 = As[kk][tm * 4 + 0], a1 = As[kk][tm * 4 + 1];
            float a2 = As[kk][tm * 4 + 2], a3 = As[kk][tm * 4 + 3];
            #pragma unroll
            for (int j = 0; j < 4; ++j){
                accr[0][j] = fmaf(a0, b4[j], accr[0][j]);
                accr[1][j] = fmaf(a1, b4[j], accr[1][j]);
                accr[2][j] = fmaf(a2, b4[j], accr[2][j]);
                accr[3][j] = fmaf(a3, b4[j], accr[3][j]);
            }
        }
    }
    float lsum = 0.f;
    #pragma unroll
    for (int i2 = 0; i2 < 4; ++i2){
        int row = bm0 + tm * 4 + i2, col = bn0 + tn * 4;
        f32x4 o;
        #pragma unroll
        for (int j = 0; j < 4; ++j){
            float cv = accr[i2][j] + bias[col + j];
            if (DOLEAKY) cv = leaky(cv);
            o[j] = cv;
        }
        if (DOLOSS){
            f32x4 fv = *(const f32x4*)&feat[(size_t)row * 512 + col];
            #pragma unroll
            for (int j = 0; j < 4; ++j){ float d = o[j] - fv[j]; lsum = fmaf(d, d, lsum); }
        }
        *(f32x4*)&Cm[(size_t)row * 512 + col] = o;
    }
    if (DOLOSS){
        red[t] = lsum; __syncthreads();
        for (int s = 128; s > 0; s >>= 1){ if (t < s) red[t] += red[t + s]; __syncthreads(); }
        if (t == 0) atomicAdd(acc + 1, red[0]);
    }
}

// ---------------------------------------------------------------------------
// K3: params = h @ enc_w2 + b2 ; mean/std/z ; KL partial. thread = (b, n<64)
// ---------------------------------------------------------------------------
__global__ __launch_bounds__(256) void k_params(
    const float* __restrict__ h, const float* __restrict__ w2,
    const float* __restrict__ b2, const float* __restrict__ eps,
    float* __restrict__ out_mean, float* __restrict__ out_std,
    float* __restrict__ zbuf, float* __restrict__ acc)
{
    int gid = blockIdx.x * 256 + threadIdx.x;
    int b = gid >> 6, n = gid & 63;
    const f32x4* h4 = (const f32x4*)(h + (size_t)b * 512);
    float a = 0.f;
    for (int kk = 0; kk < 128; ++kk){
        f32x4 hv = h4[kk];
        a = fmaf(hv[0], w2[(kk * 4 + 0) * 64 + n], a);
        a = fmaf(hv[1], w2[(kk * 4 + 1) * 64 + n], a);
        a = fmaf(hv[2], w2[(kk * 4 + 2) * 64 + n], a);
        a = fmaf(hv[3], w2[(kk * 4 + 3) * 64 + n], a);
    }
    float val = a + b2[n];
    int lane = threadIdx.x & 63;
    float ls = __shfl(val, (lane & 31) + 32);   // partner lane holds log_std
    float klp = 0.f;
    if (n < 32){
        float mean = val, stdv = expf(ls);
        float z = fmaf(stdv, eps[(size_t)b * 32 + n], mean);
        out_mean[(size_t)b * 32 + n] = mean;
        out_std [(size_t)b * 32 + n] = stdv;
        zbuf    [(size_t)b * 32 + n] = z;
        klp = mean * mean + stdv * stdv - 2.f * ls - 1.f;
    }
    #pragma unroll
    for (int off = 32; off; off >>= 1) klp += __shfl_xor(klp, off);
    if (lane == 0) atomicAdd(acc + 0, klp);
}

// ---------------------------------------------------------------------------
// K4: mech — per-i MLP. block = (i, 256 b's), thread = one b
// ---------------------------------------------------------------------------
__global__ __launch_bounds__(256) void k_mech(
    const float* __restrict__ z, const float* __restrict__ A,
    const float* __restrict__ w1, const float* __restrict__ b1,
    const float* __restrict__ w2, const float* __restrict__ b2,
    float* __restrict__ out_zc, float* __restrict__ zcbuf)
{
    __shared__ float w1t[256][36];      // [h][s], padded
    __shared__ float acol[32];
    __shared__ float b1s[256], w2s[256];
    const int t = threadIdx.x;
    const int i = blockIdx.x;
    {
        int s = t >> 3, h0 = (t & 7) * 32;
        const float* src = w1 + ((size_t)i * 32 + s) * 256 + h0;
        #pragma unroll
        for (int q = 0; q < 8; ++q){
            f32x4 v = *(const f32x4*)(src + q * 4);
            w1t[h0 + q * 4 + 0][s] = v[0]; w1t[h0 + q * 4 + 1][s] = v[1];
            w1t[h0 + q * 4 + 2][s] = v[2]; w1t[h0 + q * 4 + 3][s] = v[3];
        }
        if (t < 32) acol[t] = A[t * 32 + i];
        b1s[t] = b1[i * 256 + t];
        w2s[t] = w2[i * 256 + t];
    }
    __syncthreads();
    int b = blockIdx.y * 256 + t;
    float zA[32];
    const f32x4* z4 = (const f32x4*)(z + (size_t)b * 32);
    #pragma unroll
    for (int q = 0; q < 8; ++q){
        f32x4 v = z4[q];
        #pragma unroll
        for (int c2 = 0; c2 < 4; ++c2) zA[q * 4 + c2] = v[c2] * acol[q * 4 + c2];
    }
    float zc = 0.f;
    for (int h = 0; h < 256; ++h){
        float a = b1s[h];
        #pragma unroll
        for (int sq = 0; sq < 8; ++sq){
            f32x4 w = *(const f32x4*)&w1t[h][sq * 4];
            a = fmaf(zA[sq * 4 + 0], w[0], a);
            a = fmaf(zA[sq * 4 + 1], w[1], a);
            a = fmaf(zA[sq * 4 + 2], w[2], a);
            a = fmaf(zA[sq * 4 + 3], w[3], a);
        }
        a = leaky(a);
        zc = fmaf(a, w2s[h], zc);
    }
    zc += b2[i];
    out_zc[(size_t)b * 32 + i] = zc;
    zcbuf [(size_t)b * 32 + i] = zc;
}

// ---------------------------------------------------------------------------
// K5: d1 = leaky(z_causal @ dec_w1 + dec_b1). thread = (b, h)
// ---------------------------------------------------------------------------
__global__ __launch_bounds__(256) void k_dec1(
    const float* __restrict__ zc, const float* __restrict__ w1,
    const float* __restrict__ b1, float* __restrict__ d1)
{
    int gid = blockIdx.x * 256 + threadIdx.x;
    int b = gid >> 9, hc = gid & 511;
    const f32x4* z4 = (const f32x4*)(zc + (size_t)b * 32);
    float a = b1[hc];
    #pragma unroll
    for (int q = 0; q < 8; ++q){
        f32x4 v = z4[q];
        a = fmaf(v[0], w1[(q * 4 + 0) * 512 + hc], a);
        a = fmaf(v[1], w1[(q * 4 + 1) * 512 + hc], a);
        a = fmaf(v[2], w1[(q * 4 + 2) * 512 + hc], a);
        a = fmaf(v[3], w1[(q * 4 + 3) * 512 + hc], a);
    }
    d1[(size_t)b * 512 + hc] = leaky(a);
}

// ---------------------------------------------------------------------------
// K7: MI pair-MLPs, fused, LDS-free, MFMA 16x16x32 bf16.
// block = (p, quarter of B); each wave does independent 16-row tiles.
// A-frag: lane holds m1[b = base+(lane&15)][h = 8*(lane>>4)+i (+32*ks)]
// B-frag: lane holds w2[h = 8*(lane>>4)+i (+32*ks)][k' = (lane&15)+16*nb]
// D:      lane holds [row 4*(lane>>4)+r][col lane&15] — order-free (summed).
// ---------------------------------------------------------------------------
__global__ __launch_bounds__(256) void k_mi(
    const float* __restrict__ z, const float* __restrict__ w1g,
    const float* __restrict__ b1g, const float* __restrict__ w2g,
    const float* __restrict__ b2g, const float* __restrict__ w3g,
    float* __restrict__ macc)
{
    const int p = blockIdx.x >> 2, bq = blockIdx.x & 3;
    const int lane = threadIdx.x & 63, wv = threadIdx.x >> 6;
    const int ml = lane & 15, kg = lane >> 4;
    int pi = 0, rem = p;
    while (rem >= 31 - pi){ rem -= 31 - pi; ++pi; }
    const int pj = pi + 1 + rem;

    float w10[2][8], w11[2][8], b1r[2][8];
    s16x8 bfr[4][2];
    float w3r[4], b2r[4];
    #pragma unroll
    for (int ks = 0; ks < 2; ++ks)
        #pragma unroll
        for (int i2 = 0; i2 < 8; ++i2){
            int h = ks * 32 + kg * 8 + i2;
            w10[ks][i2] = w1g[p * 128 + h];
            w11[ks][i2] = w1g[p * 128 + 64 + h];
            b1r[ks][i2] = b1g[p * 64 + h];
        }
    #pragma unroll
    for (int nb = 0; nb < 4; ++nb){
        w3r[nb] = w3g[p * 64 + nb * 16 + ml];
        b2r[nb] = b2g[p * 64 + nb * 16 + ml];
        #pragma unroll
        for (int ks = 0; ks < 2; ++ks)
            #pragma unroll
            for (int i2 = 0; i2 < 8; ++i2){
                int h = ks * 32 + kg * 8 + i2;
                bfr[nb][ks][i2] = f2bf(w2g[(size_t)p * 4096 + h * 64 + nb * 16 + ml]);
            }
    }
    float s = 0.f;
    for (int tile = 0; tile < 16; ++tile){
        int b = bq * 1024 + (tile * 4 + wv) * 16 + ml;
        float zi = z[(size_t)b * 32 + pi], zj = z[(size_t)b * 32 + pj];
        s16x8 af[2];
        #pragma unroll
        for (int ks = 0; ks < 2; ++ks)
            #pragma unroll
            for (int i2 = 0; i2 < 8; ++i2){
                float m1 = fmaf(zj, w11[ks][i2], fmaf(zi, w10[ks][i2], b1r[ks][i2]));
                af[ks][i2] = f2bf(leaky(m1));
            }
        #pragma unroll
        for (int nb = 0; nb < 4; ++nb){
            f32x4 d = {0.f, 0.f, 0.f, 0.f};
            d = __builtin_amdgcn_mfma_f32_16x16x32_bf16(af[0], bfr[nb][0], d, 0, 0, 0);
            d = __builtin_amdgcn_mfma_f32_16x16x32_bf16(af[1], bfr[nb][1], d, 0, 0, 0);
            #pragma unroll
            for (int r2 = 0; r2 < 4; ++r2){
                float v = d[r2] + b2r[nb];
                s = fmaf(leaky(v), w3r[nb], s);
            }
        }
    }
    #pragma unroll
    for (int off = 32; off; off >>= 1) s += __shfl_xor(s, off);
    if (lane == 0) atomicAdd(&macc[p], s);
}

// ---------------------------------------------------------------------------
// K8: finalize all scalar losses
// ---------------------------------------------------------------------------
__global__ void k_final(const float* __restrict__ acc, const float* __restrict__ lw,
                        const float* __restrict__ b3, float* __restrict__ outs)
{
    __shared__ float red[512];
    int t = threadIdx.x;
    float c = 0.f;
    if (t < 496){
        int pi = 0, rem = t;
        while (rem >= 31 - pi){ rem -= 31 - pi; ++pi; }
        int pj = pi + 1 + rem;
        float est = acc[4 + t] * (1.f / 4096.f) + b3[t];
        float w = 1.f / (1.f + expf(-lw[pi * 32 + pj]));
        c = w * est;
    }
    red[t] = c; __syncthreads();
    for (int s = 256; s > 0; s >>= 1){ if (t < s) red[t] += red[t + s]; __syncthreads(); }
    if (t == 0){
        float mi    = red[0];
        float recon = acc[1] * (1.f / (4096.f * 512.f));
        float kl    = 0.5f * acc[0] * (1.f / 4096.f);
        float sp    = acc[2], dag = acc[3];
        outs[0] = recon + kl + 0.1f * sp + 0.01f * mi + dag;
        outs[1] = recon; outs[2] = kl; outs[3] = sp; outs[4] = mi; outs[5] = dag;
    }
}

// ---------------------------------------------------------------------------
extern "C" void kernel_launch(void* const* d_in, const int* in_sizes, int n_in,
                              void* d_out, int out_size, void* d_ws, size_t ws_size,
                              hipStream_t stream)
{
    const float* features = (const float*)d_in[0];
    const float* eps      = (const float*)d_in[1];
    const float* enc_w1   = (const float*)d_in[2];
    const float* enc_b1   = (const float*)d_in[3];
    const float* enc_w2   = (const float*)d_in[4];
    const float* enc_b2   = (const float*)d_in[5];
    const float* log_w    = (const float*)d_in[6];
    const float* mech_w1  = (const float*)d_in[7];
    const float* mech_b1  = (const float*)d_in[8];
    const float* mech_w2  = (const float*)d_in[9];
    const float* mech_b2  = (const float*)d_in[10];
    const float* dec_w1   = (const float*)d_in[11];
    const float* dec_b1   = (const float*)d_in[12];
    const float* dec_w2   = (const float*)d_in[13];
    const float* dec_b2   = (const float*)d_in[14];
    const float* mi_w1    = (const float*)d_in[15];
    const float* mi_b1    = (const float*)d_in[16];
    const float* mi_w2    = (const float*)d_in[17];
    const float* mi_b2    = (const float*)d_in[18];
    const float* mi_w3    = (const float*)d_in[19];
    const float* mi_b3    = (const float*)d_in[20];

    float* W      = (float*)d_ws;
    float* zbuf   = W;                 // 131072 f32
    float* zcbuf  = W + 131072;        // 131072
    float* Abuf   = W + 262144;        // 1024
    float* accums = W + 263168;        // [0]=kl [1]=recon [2]=sparsity [3]=dag [4..499]=mi_acc
    float* d1buf  = W + 264192;        // 2097152
    float* out    = (float*)d_out;
    float* hbuf   = out + 393216;      // recon region doubles as h scratch (dead after K3)

    hipMemsetAsync(accums, 0, 500 * sizeof(float), stream);
    k_setup<<<1, 1024, 0, stream>>>(log_w, Abuf, accums);
    k_gemm512<true, false><<<dim3(64, 8), 256, 0, stream>>>(features, enc_w1, enc_b1, hbuf, nullptr, nullptr);
    k_params<<<1024, 256, 0, stream>>>(hbuf, enc_w2, enc_b2, eps,
                                       out + 131072, out + 262144, zbuf, accums);
    k_mech<<<dim3(32, 16), 256, 0, stream>>>(zbuf, Abuf, mech_w1, mech_b1,
                                             mech_w2, mech_b2, out, zcbuf);
    k_dec1<<<8192, 256, 0, stream>>>(zcbuf, dec_w1, dec_b1, d1buf);
    k_gemm512<false, true><<<dim3(64, 8), 256, 0, stream>>>(d1buf, dec_w2, dec_b2,
                                                            out + 393216, features, accums);
    k_mi<<<1984, 256, 0, stream>>>(zbuf, mi_w1, mi_b1, mi_w2, mi_b2, mi_w3, accums + 4);
    k_final<<<1, 512, 0, stream>>>(accums, log_w, mi_b3, out + 2490368);
}

// Round 2
// 146.827 us; speedup vs baseline: 1.9406x; 1.9406x over previous
//
#include <hip/hip_runtime.h>

#define LEAK 0.2f

typedef float f32x4 __attribute__((ext_vector_type(4)));
typedef short s16x8 __attribute__((ext_vector_type(8)));

__device__ __forceinline__ float leaky(float x){ return fmaxf(x, 0.f) + LEAK * fminf(x, 0.f); }

__device__ __forceinline__ short f2bf(float f){
    unsigned u = __builtin_bit_cast(unsigned, f);
    u = (u + 0x7FFFu + ((u >> 16) & 1u)) >> 16;   // RNE
    return (short)u;
}

// ---------------------------------------------------------------------------
// K1: A matrix, sparsity loss, DAG loss (one block, 1024 threads)
// ---------------------------------------------------------------------------
__global__ void k_setup(const float* __restrict__ lw, float* __restrict__ A,
                        float* __restrict__ acc)
{
    __shared__ float A2s[1024], mp[1024], red[1024];
    const int t = threadIdx.x;
    const int r = t >> 5, c = t & 31;
    float v = lw[t];
    float sig = 1.f / (1.f + expf(-v));
    float l2 = (r < c) ? v * 10.f : ((r == c) ? -100.f : 0.f);
    A[t] = 1.f / (1.f + expf(-l2));
    red[t] = sig;
    float a2 = sig * sig;
    A2s[t] = a2; mp[t] = a2;
    __syncthreads();
    for (int s = 512; s > 0; s >>= 1){ if (t < s) red[t] += red[t + s]; __syncthreads(); }
    if (t == 0) acc[2] = red[0];

    const float invf[10] = {0.f, 1.f, 0.5f, 1.6666667e-1f, 4.1666667e-2f,
                            8.3333333e-3f, 1.3888889e-3f, 1.9841270e-4f,
                            2.4801587e-5f, 2.7557319e-6f};
    float tr = 0.f;
    for (int n = 1; n <= 9; ++n){
        __syncthreads();
        if (t == 0){
            float s = 0.f;
            for (int k2 = 0; k2 < 32; ++k2) s += mp[k2 * 33];
            tr += s * invf[n];
        }
        if (n == 9) break;
        float a = 0.f;
        for (int k2 = 0; k2 < 32; ++k2) a += mp[r * 32 + k2] * A2s[k2 * 32 + c];
        __syncthreads();
        mp[t] = a;
    }
    if (t == 0) acc[3] = tr * tr;
}

// ---------------------------------------------------------------------------
// K_cvt: build bf16 copies / packed MFMA B-fragment layouts.
// packed B (K x N): idx = (nt*(K/32)+kt)*512 + lane*8 + e
//   holds B[kt*32 + (lane>>4)*8 + e][nt*16 + (lane&15)]
// ---------------------------------------------------------------------------
__global__ void k_cvt(const float* __restrict__ feat, const float* __restrict__ ew1,
                      const float* __restrict__ ew2, const float* __restrict__ dw2,
                      const float* __restrict__ mw1,
                      short* __restrict__ featbf, short* __restrict__ w1p,
                      short* __restrict__ ew2p, short* __restrict__ dw2p,
                      short* __restrict__ mw1p)
{
    for (int idx = blockIdx.x * 256 + threadIdx.x; idx < 2916352; idx += gridDim.x * 256){
        if (idx < 2097152){ featbf[idx] = f2bf(feat[idx]); continue; }
        int j = idx - 2097152;
        if (j < 262144){                     // enc_w1 [512][512]
            int q = j & 511, t = j >> 9, lane = q >> 3, e = q & 7, kt = t & 15, nt = t >> 4;
            int k = kt * 32 + (lane >> 4) * 8 + e, n = nt * 16 + (lane & 15);
            w1p[j] = f2bf(ew1[k * 512 + n]); continue;
        }
        j -= 262144;
        if (j < 32768){                      // enc_w2 [512][64]
            int q = j & 511, t = j >> 9, lane = q >> 3, e = q & 7, kt = t & 15, nt = t >> 4;
            int k = kt * 32 + (lane >> 4) * 8 + e, n = nt * 16 + (lane & 15);
            ew2p[j] = f2bf(ew2[k * 64 + n]); continue;
        }
        j -= 32768;
        if (j < 262144){                     // dec_w2 [512][512]
            int q = j & 511, t = j >> 9, lane = q >> 3, e = q & 7, kt = t & 15, nt = t >> 4;
            int k = kt * 32 + (lane >> 4) * 8 + e, n = nt * 16 + (lane & 15);
            dw2p[j] = f2bf(dw2[k * 512 + n]); continue;
        }
        j -= 262144;                         // mech_w1 [32][32][256] (K=32 per i)
        int i = j >> 13, q2 = j & 8191, nt = q2 >> 9, w = q2 & 511, lane = w >> 3, e = w & 7;
        int k = (lane >> 4) * 8 + e, col = nt * 16 + (lane & 15);
        mw1p[j] = f2bf(mw1[(i * 32 + k) * 256 + col]);
    }
}

// ---------------------------------------------------------------------------
// K_genc: h = leaky(feat @ enc_w1 + b1), bf16 out. M=4096 K=512 N=512.
// LDS-free: A row-major bf16 dwordx4, B packed-frag dwordx4.
// block = 4 waves (2x2), wave tile 32x64. grid (64, 4).
// ---------------------------------------------------------------------------
__global__ __launch_bounds__(256) void k_genc(const short* __restrict__ Abf,
                                              const short* __restrict__ Bp,
                                              const float* __restrict__ bias,
                                              short* __restrict__ Hbf)
{
    const int lane = threadIdx.x & 63, wv = threadIdx.x >> 6;
    const int ml = lane & 15, kg = lane >> 4;
    const int b0 = blockIdx.x * 64 + (wv >> 1) * 32;
    const int c0 = blockIdx.y * 128 + (wv & 1) * 64;
    const int nt0 = c0 >> 4;
    f32x4 acc[2][4] = {};
    for (int kt = 0; kt < 16; ++kt){
        s16x8 a[2], b[4];
        #pragma unroll
        for (int mi = 0; mi < 2; ++mi)
            a[mi] = *(const s16x8*)&Abf[(size_t)(b0 + mi * 16 + ml) * 512 + kt * 32 + kg * 8];
        #pragma unroll
        for (int ni = 0; ni < 4; ++ni)
            b[ni] = *(const s16x8*)&Bp[((nt0 + ni) * 16 + kt) * 512 + lane * 8];
        #pragma unroll
        for (int mi = 0; mi < 2; ++mi)
            #pragma unroll
            for (int ni = 0; ni < 4; ++ni)
                acc[mi][ni] = __builtin_amdgcn_mfma_f32_16x16x32_bf16(a[mi], b[ni], acc[mi][ni], 0, 0, 0);
    }
    #pragma unroll
    for (int ni = 0; ni < 4; ++ni){
        int col = c0 + ni * 16 + ml;
        float bv = bias[col];
        #pragma unroll
        for (int mi = 0; mi < 2; ++mi)
            #pragma unroll
            for (int r = 0; r < 4; ++r){
                int row = b0 + mi * 16 + kg * 4 + r;
                Hbf[(size_t)row * 512 + col] = f2bf(leaky(acc[mi][ni][r] + bv));
            }
    }
}

// ---------------------------------------------------------------------------
// K_grec: recon = d1 @ dec_w2 + b2 (fp32 out) + recon-loss atomic.
// ---------------------------------------------------------------------------
__global__ __launch_bounds__(256) void k_grec(const short* __restrict__ Abf,
                                              const short* __restrict__ Bp,
                                              const float* __restrict__ bias,
                                              const float* __restrict__ feat,
                                              float* __restrict__ recon,
                                              float* __restrict__ accg)
{
    __shared__ float red[256];
    const int t = threadIdx.x;
    const int lane = t & 63, wv = t >> 6;
    const int ml = lane & 15, kg = lane >> 4;
    const int b0 = blockIdx.x * 64 + (wv >> 1) * 32;
    const int c0 = blockIdx.y * 128 + (wv & 1) * 64;
    const int nt0 = c0 >> 4;
    f32x4 acc[2][4] = {};
    for (int kt = 0; kt < 16; ++kt){
        s16x8 a[2], b[4];
        #pragma unroll
        for (int mi = 0; mi < 2; ++mi)
            a[mi] = *(const s16x8*)&Abf[(size_t)(b0 + mi * 16 + ml) * 512 + kt * 32 + kg * 8];
        #pragma unroll
        for (int ni = 0; ni < 4; ++ni)
            b[ni] = *(const s16x8*)&Bp[((nt0 + ni) * 16 + kt) * 512 + lane * 8];
        #pragma unroll
        for (int mi = 0; mi < 2; ++mi)
            #pragma unroll
            for (int ni = 0; ni < 4; ++ni)
                acc[mi][ni] = __builtin_amdgcn_mfma_f32_16x16x32_bf16(a[mi], b[ni], acc[mi][ni], 0, 0, 0);
    }
    float lsum = 0.f;
    #pragma unroll
    for (int ni = 0; ni < 4; ++ni){
        int col = c0 + ni * 16 + ml;
        float bv = bias[col];
        #pragma unroll
        for (int mi = 0; mi < 2; ++mi)
            #pragma unroll
            for (int r = 0; r < 4; ++r){
                int row = b0 + mi * 16 + kg * 4 + r;
                float v = acc[mi][ni][r] + bv;
                float d = v - feat[(size_t)row * 512 + col];
                lsum = fmaf(d, d, lsum);
                recon[(size_t)row * 512 + col] = v;
            }
    }
    red[t] = lsum; __syncthreads();
    for (int s = 128; s > 0; s >>= 1){ if (t < s) red[t] += red[t + s]; __syncthreads(); }
    if (t == 0) atomicAdd(accg + 1, red[0]);
}

// ---------------------------------------------------------------------------
// K_pmfma: params = h @ enc_w2 + b2 -> mean/std/z + KL. M=4096 N=64 K=512.
// block = 64 rows, wave wv owns 16 cols (n-frag wv), 4 m-frags.
// ---------------------------------------------------------------------------
__global__ __launch_bounds__(256) void k_pmfma(const short* __restrict__ Hbf,
                                               const short* __restrict__ Bp,
                                               const float* __restrict__ b2,
                                               const float* __restrict__ eps,
                                               float* __restrict__ omean,
                                               float* __restrict__ ostd,
                                               float* __restrict__ zbuf,
                                               float* __restrict__ accg)
{
    __shared__ float P[64][65];
    __shared__ float red[256];
    const int t = threadIdx.x, lane = t & 63, wv = t >> 6;
    const int ml = lane & 15, kg = lane >> 4;
    const int b0 = blockIdx.x * 64;
    f32x4 a4[4] = {};
    for (int kt = 0; kt < 16; ++kt){
        s16x8 b = *(const s16x8*)&Bp[(wv * 16 + kt) * 512 + lane * 8];
        #pragma unroll
        for (int mi = 0; mi < 4; ++mi){
            s16x8 a = *(const s16x8*)&Hbf[(size_t)(b0 + mi * 16 + ml) * 512 + kt * 32 + kg * 8];
            a4[mi] = __builtin_amdgcn_mfma_f32_16x16x32_bf16(a, b, a4[mi], 0, 0, 0);
        }
    }
    {
        int col = wv * 16 + ml;
        float bv = b2[col];
        #pragma unroll
        for (int mi = 0; mi < 4; ++mi)
            #pragma unroll
            for (int r = 0; r < 4; ++r)
                P[mi * 16 + kg * 4 + r][col] = a4[mi][r] + bv;
    }
    __syncthreads();
    float klp = 0.f;
    #pragma unroll
    for (int q = 0; q < 8; ++q){
        int e = t + q * 256;
        int row = e >> 5, n = e & 31;
        float mean = P[row][n], ls = P[row][n + 32];
        float sd = expf(ls);
        size_t o = (size_t)(b0 + row) * 32 + n;
        float z = fmaf(sd, eps[o], mean);
        omean[o] = mean; ostd[o] = sd; zbuf[o] = z;
        klp += mean * mean + sd * sd - 2.f * ls - 1.f;
    }
    red[t] = klp; __syncthreads();
    for (int s = 128; s > 0; s >>= 1){ if (t < s) red[t] += red[t + s]; __syncthreads(); }
    if (t == 0) atomicAdd(accg + 0, red[0]);
}

// ---------------------------------------------------------------------------
// K_mechm: per-i mech MLP via MFMA. grid (64 row-blocks, 32 i's).
// wave = 16 rows; h1 tile [16x256] = 16 MFMAs (K=32), fused w2-dot + reduce.
// ---------------------------------------------------------------------------
__global__ __launch_bounds__(256) void k_mechm(const float* __restrict__ z,
                                               const float* __restrict__ A,
                                               const short* __restrict__ W1p,
                                               const float* __restrict__ b1,
                                               const float* __restrict__ w2,
                                               const float* __restrict__ b2,
                                               float* __restrict__ out_zc,
                                               float* __restrict__ zcbuf)
{
    __shared__ float sA[32], sB1[256], sW2[256];
    const int t = threadIdx.x, lane = t & 63, wv = t >> 6;
    const int ml = lane & 15, kg = lane >> 4;
    const int i = blockIdx.y;
    const int b0 = blockIdx.x * 64 + wv * 16;
    if (t < 32) sA[t] = A[t * 32 + i];
    sB1[t] = b1[i * 256 + t];
    sW2[t] = w2[i * 256 + t];
    __syncthreads();
    const f32x4* zr = (const f32x4*)&z[(size_t)(b0 + ml) * 32 + kg * 8];
    f32x4 z0 = zr[0], z1 = zr[1];
    s16x8 af;
    #pragma unroll
    for (int q = 0; q < 4; ++q){
        af[q]     = f2bf(z0[q] * sA[kg * 8 + q]);
        af[q + 4] = f2bf(z1[q] * sA[kg * 8 + 4 + q]);
    }
    float s[4] = {0.f, 0.f, 0.f, 0.f};
    #pragma unroll
    for (int nt = 0; nt < 16; ++nt){
        s16x8 bf = *(const s16x8*)&W1p[i * 8192 + nt * 512 + lane * 8];
        f32x4 d = {0.f, 0.f, 0.f, 0.f};
        d = __builtin_amdgcn_mfma_f32_16x16x32_bf16(af, bf, d, 0, 0, 0);
        int col = nt * 16 + ml;
        float w2v = sW2[col], b1v = sB1[col];
        #pragma unroll
        for (int r = 0; r < 4; ++r)
            s[r] = fmaf(leaky(d[r] + b1v), w2v, s[r]);
    }
    #pragma unroll
    for (int off = 1; off < 16; off <<= 1)
        #pragma unroll
        for (int r = 0; r < 4; ++r) s[r] += __shfl_xor(s[r], off);
    if (ml == 0){
        float bb = b2[i];
        #pragma unroll
        for (int r = 0; r < 4; ++r){
            int b = b0 + kg * 4 + r;
            float zc = s[r] + bb;
            out_zc[(size_t)b * 32 + i] = zc;
            zcbuf [(size_t)b * 32 + i] = zc;
        }
    }
}

// ---------------------------------------------------------------------------
// K5: d1 = leaky(z_causal @ dec_w1 + dec_b1), bf16 out. thread = (b, h)
// ---------------------------------------------------------------------------
__global__ __launch_bounds__(256) void k_dec1(
    const float* __restrict__ zc, const float* __restrict__ w1,
    const float* __restrict__ b1, short* __restrict__ d1)
{
    int gid = blockIdx.x * 256 + threadIdx.x;
    int b = gid >> 9, hc = gid & 511;
    const f32x4* z4 = (const f32x4*)(zc + (size_t)b * 32);
    float a = b1[hc];
    #pragma unroll
    for (int q = 0; q < 8; ++q){
        f32x4 v = z4[q];
        a = fmaf(v[0], w1[(q * 4 + 0) * 512 + hc], a);
        a = fmaf(v[1], w1[(q * 4 + 1) * 512 + hc], a);
        a = fmaf(v[2], w1[(q * 4 + 2) * 512 + hc], a);
        a = fmaf(v[3], w1[(q * 4 + 3) * 512 + hc], a);
    }
    d1[(size_t)b * 512 + hc] = f2bf(leaky(a));
}

// ---------------------------------------------------------------------------
// K7: MI pair-MLPs, fused, LDS-free, MFMA 16x16x32 bf16.
// ---------------------------------------------------------------------------
__global__ __launch_bounds__(256) void k_mi(
    const float* __restrict__ z, const float* __restrict__ w1g,
    const float* __restrict__ b1g, const float* __restrict__ w2g,
    const float* __restrict__ b2g, const float* __restrict__ w3g,
    float* __restrict__ macc)
{
    const int p = blockIdx.x >> 2, bq = blockIdx.x & 3;
    const int lane = threadIdx.x & 63, wv = threadIdx.x >> 6;
    const int ml = lane & 15, kg = lane >> 4;
    int pi = 0, rem = p;
    while (rem >= 31 - pi){ rem -= 31 - pi; ++pi; }
    const int pj = pi + 1 + rem;

    float w10[2][8], w11[2][8], b1r[2][8];
    s16x8 bfr[4][2];
    float w3r[4], b2r[4];
    #pragma unroll
    for (int ks = 0; ks < 2; ++ks)
        #pragma unroll
        for (int i2 = 0; i2 < 8; ++i2){
            int h = ks * 32 + kg * 8 + i2;
            w10[ks][i2] = w1g[p * 128 + h];
            w11[ks][i2] = w1g[p * 128 + 64 + h];
            b1r[ks][i2] = b1g[p * 64 + h];
        }
    #pragma unroll
    for (int nb = 0; nb < 4; ++nb){
        w3r[nb] = w3g[p * 64 + nb * 16 + ml];
        b2r[nb] = b2g[p * 64 + nb * 16 + ml];
        #pragma unroll
        for (int ks = 0; ks < 2; ++ks)
            #pragma unroll
            for (int i2 = 0; i2 < 8; ++i2){
                int h = ks * 32 + kg * 8 + i2;
                bfr[nb][ks][i2] = f2bf(w2g[(size_t)p * 4096 + h * 64 + nb * 16 + ml]);
            }
    }
    float s = 0.f;
    for (int tile = 0; tile < 16; ++tile){
        int b = bq * 1024 + (tile * 4 + wv) * 16 + ml;
        float zi = z[(size_t)b * 32 + pi], zj = z[(size_t)b * 32 + pj];
        s16x8 af[2];
        #pragma unroll
        for (int ks = 0; ks < 2; ++ks)
            #pragma unroll
            for (int i2 = 0; i2 < 8; ++i2){
                float m1 = fmaf(zj, w11[ks][i2], fmaf(zi, w10[ks][i2], b1r[ks][i2]));
                af[ks][i2] = f2bf(leaky(m1));
            }
        #pragma unroll
        for (int nb = 0; nb < 4; ++nb){
            f32x4 d = {0.f, 0.f, 0.f, 0.f};
            d = __builtin_amdgcn_mfma_f32_16x16x32_bf16(af[0], bfr[nb][0], d, 0, 0, 0);
            d = __builtin_amdgcn_mfma_f32_16x16x32_bf16(af[1], bfr[nb][1], d, 0, 0, 0);
            #pragma unroll
            for (int r2 = 0; r2 < 4; ++r2){
                float v = d[r2] + b2r[nb];
                s = fmaf(leaky(v), w3r[nb], s);
            }
        }
    }
    #pragma unroll
    for (int off = 32; off; off >>= 1) s += __shfl_xor(s, off);
    if (lane == 0) atomicAdd(&macc[p], s);
}

// ---------------------------------------------------------------------------
// K8: finalize all scalar losses
// ---------------------------------------------------------------------------
__global__ void k_final(const float* __restrict__ acc, const float* __restrict__ lw,
                        const float* __restrict__ b3, float* __restrict__ outs)
{
    __shared__ float red[512];
    int t = threadIdx.x;
    float c = 0.f;
    if (t < 496){
        int pi = 0, rem = t;
        while (rem >= 31 - pi){ rem -= 31 - pi; ++pi; }
        int pj = pi + 1 + rem;
        float est = acc[4 + t] * (1.f / 4096.f) + b3[t];
        float w = 1.f / (1.f + expf(-lw[pi * 32 + pj]));
        c = w * est;
    }
    red[t] = c; __syncthreads();
    for (int s = 256; s > 0; s >>= 1){ if (t < s) red[t] += red[t + s]; __syncthreads(); }
    if (t == 0){
        float mi    = red[0];
        float recon = acc[1] * (1.f / (4096.f * 512.f));
        float kl    = 0.5f * acc[0] * (1.f / 4096.f);
        float sp    = acc[2], dag = acc[3];
        outs[0] = recon + kl + 0.1f * sp + 0.01f * mi + dag;
        outs[1] = recon; outs[2] = kl; outs[3] = sp; outs[4] = mi; outs[5] = dag;
    }
}

// ---------------------------------------------------------------------------
extern "C" void kernel_launch(void* const* d_in, const int* in_sizes, int n_in,
                              void* d_out, int out_size, void* d_ws, size_t ws_size,
                              hipStream_t stream)
{
    const float* features = (const float*)d_in[0];
    const float* eps      = (const float*)d_in[1];
    const float* enc_w1   = (const float*)d_in[2];
    const float* enc_b1   = (const float*)d_in[3];
    const float* enc_w2   = (const float*)d_in[4];
    const float* enc_b2   = (const float*)d_in[5];
    const float* log_w    = (const float*)d_in[6];
    const float* mech_w1  = (const float*)d_in[7];
    const float* mech_b1  = (const float*)d_in[8];
    const float* mech_w2  = (const float*)d_in[9];
    const float* mech_b2  = (const float*)d_in[10];
    const float* dec_w1   = (const float*)d_in[11];
    const float* dec_b1   = (const float*)d_in[12];
    const float* dec_w2   = (const float*)d_in[13];
    const float* dec_b2   = (const float*)d_in[14];
    const float* mi_w1    = (const float*)d_in[15];
    const float* mi_b1    = (const float*)d_in[16];
    const float* mi_w2    = (const float*)d_in[17];
    const float* mi_b2    = (const float*)d_in[18];
    const float* mi_w3    = (const float*)d_in[19];
    const float* mi_b3    = (const float*)d_in[20];

    float* W      = (float*)d_ws;
    float* zbuf   = W;                         // 131072 f32
    float* zcbuf  = W + 131072;                // 131072
    float* Abuf   = W + 262144;                // 1024
    float* accums = W + 263168;                // 512: [0]=kl [1]=recon [2]=sp [3]=dag [4..499]=mi
    short* w1p    = (short*)(W + 263680);      // 262144 bf16 (enc_w1 packed)
    short* ew2p   = (short*)(W + 394752);      // 32768 bf16
    short* dw2p   = (short*)(W + 411136);      // 262144 bf16
    short* mw1p   = (short*)(W + 542208);      // 262144 bf16
    short* d1bf   = (short*)(W + 673280);      // 2097152 bf16
    float* out    = (float*)d_out;
    // dead recon region doubles as scratch until k_grec writes it:
    short* featbf = (short*)(out + 393216);            // 2097152 bf16
    short* hbf    = (short*)(out + 393216 + 1048576);  // 2097152 bf16

    hipMemsetAsync(accums, 0, 512 * sizeof(float), stream);
    k_setup<<<1, 1024, 0, stream>>>(log_w, Abuf, accums);
    k_cvt<<<2048, 256, 0, stream>>>(features, enc_w1, enc_w2, dec_w2, mech_w1,
                                    featbf, w1p, ew2p, dw2p, mw1p);
    k_genc<<<dim3(64, 4), 256, 0, stream>>>(featbf, w1p, enc_b1, hbf);
    k_pmfma<<<64, 256, 0, stream>>>(hbf, ew2p, enc_b2, eps,
                                    out + 131072, out + 262144, zbuf, accums);
    k_mechm<<<dim3(64, 32), 256, 0, stream>>>(zbuf, Abuf, mw1p, mech_b1,
                                              mech_w2, mech_b2, out, zcbuf);
    k_dec1<<<8192, 256, 0, stream>>>(zcbuf, dec_w1, dec_b1, d1bf);
    k_grec<<<dim3(64, 4), 256, 0, stream>>>(d1bf, dw2p, dec_b2, features,
                                            out + 393216, accums);
    k_mi<<<1984, 256, 0, stream>>>(zbuf, mi_w1, mi_b1, mi_w2, mi_b2, mi_w3, accums + 4);
    k_final<<<1, 512, 0, stream>>>(accums, log_w, mi_b3, out + 2490368);
}

// Round 3
// 139.016 us; speedup vs baseline: 2.0496x; 1.0562x over previous
//
#include <hip/hip_runtime.h>
#include <hip/hip_bf16.h>

typedef float f32x4 __attribute__((ext_vector_type(4)));
typedef short s16x8 __attribute__((ext_vector_type(8)));

__device__ __forceinline__ float leaky2(float x){ return fmaf(0.4f, fabsf(x), 0.6f * x); }

__device__ __forceinline__ short f2bf(float f){
    return __builtin_bit_cast(short, __float2bfloat16(f));
}

// ---------------------------------------------------------------------------
// K1: A matrix, sparsity loss, DAG loss (one block, 1024 threads)
// ---------------------------------------------------------------------------
__global__ void k_setup(const float* __restrict__ lw, float* __restrict__ A,
                        float* __restrict__ acc)
{
    __shared__ float A2s[1024], mp[1024], red[1024];
    const int t = threadIdx.x;
    const int r = t >> 5, c = t & 31;
    float v = lw[t];
    float sig = 1.f / (1.f + expf(-v));
    float l2 = (r < c) ? v * 10.f : ((r == c) ? -100.f : 0.f);
    A[t] = 1.f / (1.f + expf(-l2));
    red[t] = sig;
    float a2 = sig * sig;
    A2s[t] = a2; mp[t] = a2;
    __syncthreads();
    for (int s = 512; s > 0; s >>= 1){ if (t < s) red[t] += red[t + s]; __syncthreads(); }
    if (t == 0) acc[2] = red[0];

    const float invf[10] = {0.f, 1.f, 0.5f, 1.6666667e-1f, 4.1666667e-2f,
                            8.3333333e-3f, 1.3888889e-3f, 1.9841270e-4f,
                            2.4801587e-5f, 2.7557319e-6f};
    float tr = 0.f;
    for (int n = 1; n <= 9; ++n){
        __syncthreads();
        if (t == 0){
            float s = 0.f;
            for (int k2 = 0; k2 < 32; ++k2) s += mp[k2 * 33];
            tr += s * invf[n];
        }
        if (n == 9) break;
        float a = 0.f;
        for (int k2 = 0; k2 < 32; ++k2) a += mp[r * 32 + k2] * A2s[k2 * 32 + c];
        __syncthreads();
        mp[t] = a;
    }
    if (t == 0) acc[3] = tr * tr;
}

// ---------------------------------------------------------------------------
// K_cvt: build bf16 copies / packed MFMA B-fragment layouts.
// ---------------------------------------------------------------------------
__global__ void k_cvt(const float* __restrict__ feat, const float* __restrict__ ew1,
                      const float* __restrict__ ew2, const float* __restrict__ dw2,
                      const float* __restrict__ mw1,
                      short* __restrict__ featbf, short* __restrict__ w1p,
                      short* __restrict__ ew2p, short* __restrict__ dw2p,
                      short* __restrict__ mw1p)
{
    for (int idx = blockIdx.x * 256 + threadIdx.x; idx < 2916352; idx += gridDim.x * 256){
        if (idx < 2097152){ featbf[idx] = f2bf(feat[idx]); continue; }
        int j = idx - 2097152;
        if (j < 262144){                     // enc_w1 [512][512]
            int q = j & 511, t = j >> 9, lane = q >> 3, e = q & 7, kt = t & 15, nt = t >> 4;
            int k = kt * 32 + (lane >> 4) * 8 + e, n = nt * 16 + (lane & 15);
            w1p[j] = f2bf(ew1[k * 512 + n]); continue;
        }
        j -= 262144;
        if (j < 32768){                      // enc_w2 [512][64]
            int q = j & 511, t = j >> 9, lane = q >> 3, e = q & 7, kt = t & 15, nt = t >> 4;
            int k = kt * 32 + (lane >> 4) * 8 + e, n = nt * 16 + (lane & 15);
            ew2p[j] = f2bf(ew2[k * 64 + n]); continue;
        }
        j -= 32768;
        if (j < 262144){                     // dec_w2 [512][512]
            int q = j & 511, t = j >> 9, lane = q >> 3, e = q & 7, kt = t & 15, nt = t >> 4;
            int k = kt * 32 + (lane >> 4) * 8 + e, n = nt * 16 + (lane & 15);
            dw2p[j] = f2bf(dw2[k * 512 + n]); continue;
        }
        j -= 262144;                         // mech_w1 [32][32][256]
        int i = j >> 13, q2 = j & 8191, nt = q2 >> 9, w = q2 & 511, lane = w >> 3, e = w & 7;
        int k = (lane >> 4) * 8 + e, col = nt * 16 + (lane & 15);
        mw1p[j] = f2bf(mw1[(i * 32 + k) * 256 + col]);
    }
}

// ---------------------------------------------------------------------------
// K_genc: h = leaky(feat @ enc_w1 + b1), bf16 out. LDS-free MFMA.
// ---------------------------------------------------------------------------
__global__ __launch_bounds__(256) void k_genc(const short* __restrict__ Abf,
                                              const short* __restrict__ Bp,
                                              const float* __restrict__ bias,
                                              short* __restrict__ Hbf)
{
    const int lane = threadIdx.x & 63, wv = threadIdx.x >> 6;
    const int ml = lane & 15, kg = lane >> 4;
    const int b0 = blockIdx.x * 64 + (wv >> 1) * 32;
    const int c0 = blockIdx.y * 128 + (wv & 1) * 64;
    const int nt0 = c0 >> 4;
    f32x4 acc[2][4] = {};
    for (int kt = 0; kt < 16; ++kt){
        s16x8 a[2], b[4];
        #pragma unroll
        for (int mi = 0; mi < 2; ++mi)
            a[mi] = *(const s16x8*)&Abf[(size_t)(b0 + mi * 16 + ml) * 512 + kt * 32 + kg * 8];
        #pragma unroll
        for (int ni = 0; ni < 4; ++ni)
            b[ni] = *(const s16x8*)&Bp[((nt0 + ni) * 16 + kt) * 512 + lane * 8];
        #pragma unroll
        for (int mi = 0; mi < 2; ++mi)
            #pragma unroll
            for (int ni = 0; ni < 4; ++ni)
                acc[mi][ni] = __builtin_amdgcn_mfma_f32_16x16x32_bf16(a[mi], b[ni], acc[mi][ni], 0, 0, 0);
    }
    #pragma unroll
    for (int ni = 0; ni < 4; ++ni){
        int col = c0 + ni * 16 + ml;
        float bv = bias[col];
        #pragma unroll
        for (int mi = 0; mi < 2; ++mi)
            #pragma unroll
            for (int r = 0; r < 4; ++r){
                int row = b0 + mi * 16 + kg * 4 + r;
                Hbf[(size_t)row * 512 + col] = f2bf(leaky2(acc[mi][ni][r] + bv));
            }
    }
}

// ---------------------------------------------------------------------------
// K_grec: recon = d1 @ dec_w2 + b2 (fp32 out) + recon-loss atomic.
// ---------------------------------------------------------------------------
__global__ __launch_bounds__(256) void k_grec(const short* __restrict__ Abf,
                                              const short* __restrict__ Bp,
                                              const float* __restrict__ bias,
                                              const float* __restrict__ feat,
                                              float* __restrict__ recon,
                                              float* __restrict__ accg)
{
    __shared__ float red[256];
    const int t = threadIdx.x;
    const int lane = t & 63, wv = t >> 6;
    const int ml = lane & 15, kg = lane >> 4;
    const int b0 = blockIdx.x * 64 + (wv >> 1) * 32;
    const int c0 = blockIdx.y * 128 + (wv & 1) * 64;
    const int nt0 = c0 >> 4;
    f32x4 acc[2][4] = {};
    for (int kt = 0; kt < 16; ++kt){
        s16x8 a[2], b[4];
        #pragma unroll
        for (int mi = 0; mi < 2; ++mi)
            a[mi] = *(const s16x8*)&Abf[(size_t)(b0 + mi * 16 + ml) * 512 + kt * 32 + kg * 8];
        #pragma unroll
        for (int ni = 0; ni < 4; ++ni)
            b[ni] = *(const s16x8*)&Bp[((nt0 + ni) * 16 + kt) * 512 + lane * 8];
        #pragma unroll
        for (int mi = 0; mi < 2; ++mi)
            #pragma unroll
            for (int ni = 0; ni < 4; ++ni)
                acc[mi][ni] = __builtin_amdgcn_mfma_f32_16x16x32_bf16(a[mi], b[ni], acc[mi][ni], 0, 0, 0);
    }
    float lsum = 0.f;
    #pragma unroll
    for (int ni = 0; ni < 4; ++ni){
        int col = c0 + ni * 16 + ml;
        float bv = bias[col];
        #pragma unroll
        for (int mi = 0; mi < 2; ++mi)
            #pragma unroll
            for (int r = 0; r < 4; ++r){
                int row = b0 + mi * 16 + kg * 4 + r;
                float v = acc[mi][ni][r] + bv;
                float d = v - feat[(size_t)row * 512 + col];
                lsum = fmaf(d, d, lsum);
                recon[(size_t)row * 512 + col] = v;
            }
    }
    red[t] = lsum; __syncthreads();
    for (int s = 128; s > 0; s >>= 1){ if (t < s) red[t] += red[t + s]; __syncthreads(); }
    if (t == 0) atomicAdd(accg + 1, red[0]);
}

// ---------------------------------------------------------------------------
// K_pmfma: params -> mean/std/z + KL. 256 blocks x 16 rows (was 64 blocks).
// ---------------------------------------------------------------------------
__global__ __launch_bounds__(256) void k_pmfma(const short* __restrict__ Hbf,
                                               const short* __restrict__ Bp,
                                               const float* __restrict__ b2,
                                               const float* __restrict__ eps,
                                               float* __restrict__ omean,
                                               float* __restrict__ ostd,
                                               float* __restrict__ zbuf,
                                               float* __restrict__ accg)
{
    __shared__ float P[16][65];
    __shared__ float red[256];
    const int t = threadIdx.x, lane = t & 63, wv = t >> 6;
    const int ml = lane & 15, kg = lane >> 4;
    const int b0 = blockIdx.x * 16;
    f32x4 acc = {};
    for (int kt = 0; kt < 16; ++kt){
        s16x8 b = *(const s16x8*)&Bp[(wv * 16 + kt) * 512 + lane * 8];
        s16x8 a = *(const s16x8*)&Hbf[(size_t)(b0 + ml) * 512 + kt * 32 + kg * 8];
        acc = __builtin_amdgcn_mfma_f32_16x16x32_bf16(a, b, acc, 0, 0, 0);
    }
    {
        int col = wv * 16 + ml;
        float bv = b2[col];
        #pragma unroll
        for (int r = 0; r < 4; ++r)
            P[kg * 4 + r][col] = acc[r] + bv;
    }
    __syncthreads();
    float klp = 0.f;
    #pragma unroll
    for (int q = 0; q < 2; ++q){
        int e = q * 256 + t;
        int row = e >> 5, n = e & 31;
        float mean = P[row][n], ls = P[row][n + 32];
        float sd = expf(ls);
        size_t o = (size_t)(b0 + row) * 32 + n;
        float z = fmaf(sd, eps[o], mean);
        omean[o] = mean; ostd[o] = sd; zbuf[o] = z;
        klp += mean * mean + sd * sd - 2.f * ls - 1.f;
    }
    red[t] = klp; __syncthreads();
    for (int s = 128; s > 0; s >>= 1){ if (t < s) red[t] += red[t + s]; __syncthreads(); }
    if (t == 0) atomicAdd(accg + 0, red[0]);
}

// ---------------------------------------------------------------------------
// K_mechm: per-i mech MLP via MFMA; bias via C-in, leaky*w2 as 2 FMAs.
// ---------------------------------------------------------------------------
__global__ __launch_bounds__(256) void k_mechm(const float* __restrict__ z,
                                               const float* __restrict__ A,
                                               const short* __restrict__ W1p,
                                               const float* __restrict__ b1,
                                               const float* __restrict__ w2,
                                               const float* __restrict__ b2,
                                               float* __restrict__ out_zc,
                                               float* __restrict__ zcbuf)
{
    __shared__ float sA[32], sB1[256], sW2[256];
    const int t = threadIdx.x, lane = t & 63, wv = t >> 6;
    const int ml = lane & 15, kg = lane >> 4;
    const int i = blockIdx.y;
    const int b0 = blockIdx.x * 64 + wv * 16;
    if (t < 32) sA[t] = A[t * 32 + i];
    sB1[t] = b1[i * 256 + t];
    sW2[t] = w2[i * 256 + t];
    __syncthreads();
    const f32x4* zr = (const f32x4*)&z[(size_t)(b0 + ml) * 32 + kg * 8];
    f32x4 z0 = zr[0], z1 = zr[1];
    s16x8 af;
    #pragma unroll
    for (int q = 0; q < 4; ++q){
        af[q]     = f2bf(z0[q] * sA[kg * 8 + q]);
        af[q + 4] = f2bf(z1[q] * sA[kg * 8 + 4 + q]);
    }
    float s[4] = {0.f, 0.f, 0.f, 0.f};
    #pragma unroll
    for (int nt = 0; nt < 16; ++nt){
        s16x8 bf = *(const s16x8*)&W1p[i * 8192 + nt * 512 + lane * 8];
        int col = nt * 16 + ml;
        float b1v = sB1[col], w2v = sW2[col];
        f32x4 d = {b1v, b1v, b1v, b1v};
        d = __builtin_amdgcn_mfma_f32_16x16x32_bf16(af, bf, d, 0, 0, 0);
        float w2a = 0.6f * w2v, w2b = 0.4f * w2v;
        #pragma unroll
        for (int r = 0; r < 4; ++r)
            s[r] = fmaf(w2a, d[r], fmaf(w2b, fabsf(d[r]), s[r]));
    }
    #pragma unroll
    for (int off = 1; off < 16; off <<= 1)
        #pragma unroll
        for (int r = 0; r < 4; ++r) s[r] += __shfl_xor(s[r], off);
    if (ml == 0){
        float bb = b2[i];
        #pragma unroll
        for (int r = 0; r < 4; ++r){
            int b = b0 + kg * 4 + r;
            float zc = s[r] + bb;
            out_zc[(size_t)b * 32 + i] = zc;
            zcbuf [(size_t)b * 32 + i] = zc;
        }
    }
}

// ---------------------------------------------------------------------------
// K5: d1 = leaky(z_causal @ dec_w1 + dec_b1), bf16 out.
// ---------------------------------------------------------------------------
__global__ __launch_bounds__(256) void k_dec1(
    const float* __restrict__ zc, const float* __restrict__ w1,
    const float* __restrict__ b1, short* __restrict__ d1)
{
    int gid = blockIdx.x * 256 + threadIdx.x;
    int b = gid >> 9, hc = gid & 511;
    const f32x4* z4 = (const f32x4*)(zc + (size_t)b * 32);
    float a = b1[hc];
    #pragma unroll
    for (int q = 0; q < 8; ++q){
        f32x4 v = z4[q];
        a = fmaf(v[0], w1[(q * 4 + 0) * 512 + hc], a);
        a = fmaf(v[1], w1[(q * 4 + 1) * 512 + hc], a);
        a = fmaf(v[2], w1[(q * 4 + 2) * 512 + hc], a);
        a = fmaf(v[3], w1[(q * 4 + 3) * 512 + hc], a);
    }
    d1[(size_t)b * 512 + hc] = f2bf(leaky2(a));
}

// ---------------------------------------------------------------------------
// K7: MI pair-MLPs. Layer-1: 3 FMA/elem (prescaled 0.6 weights + abs-mod
// leaky). Layer-2 bias via MFMA C-in. Layer-3: 2 FMA/elem.
// ---------------------------------------------------------------------------
__global__ __launch_bounds__(256) void k_mi(
    const float* __restrict__ z, const float* __restrict__ w1g,
    const float* __restrict__ b1g, const float* __restrict__ w2g,
    const float* __restrict__ b2g, const float* __restrict__ w3g,
    float* __restrict__ macc)
{
    const int p = blockIdx.x >> 2, bq = blockIdx.x & 3;
    const int lane = threadIdx.x & 63, wv = threadIdx.x >> 6;
    const int ml = lane & 15, kg = lane >> 4;
    int pi = 0, rem = p;
    while (rem >= 31 - pi){ rem -= 31 - pi; ++pi; }
    const int pj = pi + 1 + rem;

    float w10s[2][8], w11s[2][8], b1s[2][8];
    s16x8 bfr[4][2];
    float w3a[4], w3b[4], b2r[4];
    #pragma unroll
    for (int ks = 0; ks < 2; ++ks)
        #pragma unroll
        for (int i2 = 0; i2 < 8; ++i2){
            int h = ks * 32 + kg * 8 + i2;
            w10s[ks][i2] = 0.6f * w1g[p * 128 + h];
            w11s[ks][i2] = 0.6f * w1g[p * 128 + 64 + h];
            b1s[ks][i2]  = 0.6f * b1g[p * 64 + h];
        }
    #pragma unroll
    for (int nb = 0; nb < 4; ++nb){
        float w3 = w3g[p * 64 + nb * 16 + ml];
        w3a[nb] = 0.6f * w3; w3b[nb] = 0.4f * w3;
        b2r[nb] = b2g[p * 64 + nb * 16 + ml];
        #pragma unroll
        for (int ks = 0; ks < 2; ++ks)
            #pragma unroll
            for (int i2 = 0; i2 < 8; ++i2){
                int h = ks * 32 + kg * 8 + i2;
                bfr[nb][ks][i2] = f2bf(w2g[(size_t)p * 4096 + h * 64 + nb * 16 + ml]);
            }
    }
    float s = 0.f;
    for (int tile = 0; tile < 16; ++tile){
        int b = bq * 1024 + (tile * 4 + wv) * 16 + ml;
        float zi = z[(size_t)b * 32 + pi], zj = z[(size_t)b * 32 + pj];
        s16x8 af[2];
        #pragma unroll
        for (int ks = 0; ks < 2; ++ks)
            #pragma unroll
            for (int i2 = 0; i2 < 8; ++i2){
                float m = fmaf(zi, w10s[ks][i2], fmaf(zj, w11s[ks][i2], b1s[ks][i2]));
                m = fmaf(0.66666669f, fabsf(m), m);     // leaky, prescaled by 0.6
                af[ks][i2] = f2bf(m);
            }
        #pragma unroll
        for (int nb = 0; nb < 4; ++nb){
            f32x4 d = {b2r[nb], b2r[nb], b2r[nb], b2r[nb]};
            d = __builtin_amdgcn_mfma_f32_16x16x32_bf16(af[0], bfr[nb][0], d, 0, 0, 0);
            d = __builtin_amdgcn_mfma_f32_16x16x32_bf16(af[1], bfr[nb][1], d, 0, 0, 0);
            #pragma unroll
            for (int r2 = 0; r2 < 4; ++r2)
                s = fmaf(w3a[nb], d[r2], fmaf(w3b[nb], fabsf(d[r2]), s));
        }
    }
    #pragma unroll
    for (int off = 32; off; off >>= 1) s += __shfl_xor(s, off);
    if (lane == 0) atomicAdd(&macc[p], s);
}

// ---------------------------------------------------------------------------
// K8: finalize all scalar losses
// ---------------------------------------------------------------------------
__global__ void k_final(const float* __restrict__ acc, const float* __restrict__ lw,
                        const float* __restrict__ b3, float* __restrict__ outs)
{
    __shared__ float red[512];
    int t = threadIdx.x;
    float c = 0.f;
    if (t < 496){
        int pi = 0, rem = t;
        while (rem >= 31 - pi){ rem -= 31 - pi; ++pi; }
        int pj = pi + 1 + rem;
        float est = acc[4 + t] * (1.f / 4096.f) + b3[t];
        float w = 1.f / (1.f + expf(-lw[pi * 32 + pj]));
        c = w * est;
    }
    red[t] = c; __syncthreads();
    for (int s = 256; s > 0; s >>= 1){ if (t < s) red[t] += red[t + s]; __syncthreads(); }
    if (t == 0){
        float mi    = red[0];
        float recon = acc[1] * (1.f / (4096.f * 512.f));
        float kl    = 0.5f * acc[0] * (1.f / 4096.f);
        float sp    = acc[2], dag = acc[3];
        outs[0] = recon + kl + 0.1f * sp + 0.01f * mi + dag;
        outs[1] = recon; outs[2] = kl; outs[3] = sp; outs[4] = mi; outs[5] = dag;
    }
}

// ---------------------------------------------------------------------------
extern "C" void kernel_launch(void* const* d_in, const int* in_sizes, int n_in,
                              void* d_out, int out_size, void* d_ws, size_t ws_size,
                              hipStream_t stream)
{
    const float* features = (const float*)d_in[0];
    const float* eps      = (const float*)d_in[1];
    const float* enc_w1   = (const float*)d_in[2];
    const float* enc_b1   = (const float*)d_in[3];
    const float* enc_w2   = (const float*)d_in[4];
    const float* enc_b2   = (const float*)d_in[5];
    const float* log_w    = (const float*)d_in[6];
    const float* mech_w1  = (const float*)d_in[7];
    const float* mech_b1  = (const float*)d_in[8];
    const float* mech_w2  = (const float*)d_in[9];
    const float* mech_b2  = (const float*)d_in[10];
    const float* dec_w1   = (const float*)d_in[11];
    const float* dec_b1   = (const float*)d_in[12];
    const float* dec_w2   = (const float*)d_in[13];
    const float* dec_b2   = (const float*)d_in[14];
    const float* mi_w1    = (const float*)d_in[15];
    const float* mi_b1    = (const float*)d_in[16];
    const float* mi_w2    = (const float*)d_in[17];
    const float* mi_b2    = (const float*)d_in[18];
    const float* mi_w3    = (const float*)d_in[19];
    const float* mi_b3    = (const float*)d_in[20];

    float* W      = (float*)d_ws;
    float* zbuf   = W;                         // 131072 f32
    float* zcbuf  = W + 131072;                // 131072
    float* Abuf   = W + 262144;                // 1024
    float* accums = W + 263168;                // 512
    short* w1p    = (short*)(W + 263680);      // 262144 bf16
    short* ew2p   = (short*)(W + 394752);      // 32768 bf16
    short* dw2p   = (short*)(W + 411136);      // 262144 bf16
    short* mw1p   = (short*)(W + 542208);      // 262144 bf16
    short* d1bf   = (short*)(W + 673280);      // 2097152 bf16
    float* out    = (float*)d_out;
    short* featbf = (short*)(out + 393216);            // scratch in dead recon region
    short* hbf    = (short*)(out + 393216 + 1048576);

    hipMemsetAsync(accums, 0, 512 * sizeof(float), stream);
    k_setup<<<1, 1024, 0, stream>>>(log_w, Abuf, accums);
    k_cvt<<<2048, 256, 0, stream>>>(features, enc_w1, enc_w2, dec_w2, mech_w1,
                                    featbf, w1p, ew2p, dw2p, mw1p);
    k_genc<<<dim3(64, 4), 256, 0, stream>>>(featbf, w1p, enc_b1, hbf);
    k_pmfma<<<256, 256, 0, stream>>>(hbf, ew2p, enc_b2, eps,
                                     out + 131072, out + 262144, zbuf, accums);
    k_mechm<<<dim3(64, 32), 256, 0, stream>>>(zbuf, Abuf, mw1p, mech_b1,
                                              mech_w2, mech_b2, out, zcbuf);
    k_dec1<<<8192, 256, 0, stream>>>(zcbuf, dec_w1, dec_b1, d1bf);
    k_grec<<<dim3(64, 4), 256, 0, stream>>>(d1bf, dw2p, dec_b2, features,
                                            out + 393216, accums);
    k_mi<<<1984, 256, 0, stream>>>(zbuf, mi_w1, mi_b1, mi_w2, mi_b2, mi_w3, accums + 4);
    k_final<<<1, 512, 0, stream>>>(accums, log_w, mi_b3, out + 2490368);
}